// Round 7
// baseline (77.221 us; speedup 1.0000x reference)
//
#include <hip/hip_runtime.h>
#include <hip/hip_bf16.h>

// Problem constants (DistanceProbe): B=8, S=512, D=1024, R=128
constexpr int B_ = 8;
constexpr int S_ = 512;
constexpr int D_ = 1024;
constexpr int R_ = 128;
constexpr int M_ = B_ * S_;   // 4096 rows of T

typedef unsigned short u16;
typedef __attribute__((ext_vector_type(8))) short short8;  // 8 bf16 (4 VGPRs) MFMA A/B frag
typedef __attribute__((ext_vector_type(4))) float f32x4;   // MFMA C/D frag

// fp32 -> bf16 round-to-nearest-even (no NaN handling needed for this data)
static __device__ __forceinline__ u16 f2bf(float f) {
    unsigned u = __float_as_uint(f);
    u += 0x7fffu + ((u >> 16) & 1u);
    return (u16)(u >> 16);
}
static __device__ __forceinline__ float bf2f(u16 u) {
    return __uint_as_float((unsigned)u << 16);
}

// ---------------------------------------------------------------------------
// Kernel 1: proj [1024][128] fp32 -> Pt [16 ktiles][128 cols][64 k] bf16.
// Grid (16,4) = 64 blocks: blockIdx.x = k-tile (64 ks), blockIdx.y = kq
// (16-k subtile). Each block: 16 k x 128 cols.
// Pt element index = kk*8192 + col*64 + (kq*16 + h*8 + e)  [klocal 0..63].
// ---------------------------------------------------------------------------
__global__ __launch_bounds__(256) void transpose_proj_kernel(
    const float* __restrict__ P, u16* __restrict__ Pt)
{
    __shared__ float S[16][132];        // row stride 528 B (16B-aligned)
    const int t  = threadIdx.x;
    const int kk = blockIdx.x;          // k-tile of 64
    const int kq = blockIdx.y;          // 16-k subtile 0..3

    // load 16 k x 128 c fp32, 2 float4 per thread, coalesced
#pragma unroll
    for (int p = 0; p < 2; ++p) {
        const int k = (t >> 5) + p * 8;       // 0..15
        const int c = (t & 31) * 4;           // 0..124
        *reinterpret_cast<float4*>(&S[k][c]) =
            *reinterpret_cast<const float4*>(
                &P[(size_t)(kk * 64 + kq * 16 + k) * R_ + c]);
    }
    __syncthreads();

    // write transposed+converted: thread -> (col, 8 ks) = one uint4
    const int col = t >> 1;     // 0..127
    const int h   = t & 1;      // k-octet within the 16-k subtile
    unsigned u[4];
#pragma unroll
    for (int q = 0; q < 4; ++q) {
        const u16 lo = f2bf(S[h * 8 + q * 2 + 0][col]);
        const u16 hi = f2bf(S[h * 8 + q * 2 + 1][col]);
        u[q] = (unsigned)lo | ((unsigned)hi << 16);
    }
    *reinterpret_cast<uint4*>(&Pt[(size_t)kk * 8192 + col * 64 + kq * 16 + h * 8]) =
        make_uint4(u[0], u[1], u[2], u[3]);
}

// ---------------------------------------------------------------------------
// Kernel 2: T[4096][128] bf16 = batch[4096][1024] @ proj  via bf16 MFMA.
// Grid (2, 256) = 512 blocks (2/CU -> 2 waves/SIMD). Block: 16 rows x 64 cols.
// Wave w owns cols col0 + w*16 .. +15 (one 16x16 frag, K accumulated).
// One-tile register prefetch: tile kk+1's global loads issued right after
// tile kk's LDS writes free the registers; reg-dest loads stay in flight
// across the barriers (no vmcnt drain for VGPR loads at __syncthreads).
// A/B fragments use the same k-map kappa(g,e)=g*8+e (consistent => correct
// under any HW k-permutation). C/D layout per m89: col=l&15, row=(l>>4)*4+reg.
// LDS rows padded to 72 bf16 (144 B) -> b128 reads 2-way max (free, m136).
// ---------------------------------------------------------------------------
__global__ __launch_bounds__(256) void gemm1_kernel(
    const float* __restrict__ A,    // batch [4096][1024] fp32
    const u16* __restrict__ Pt,     // [16][128][64] bf16 (proj^T tiled)
    u16* __restrict__ T)            // [4096][128] bf16
{
    __shared__ u16 As[16][72];      // [row][k]
    __shared__ u16 Bs[64][72];      // [col-local][k]

    const int t    = threadIdx.x;
    const int row0 = blockIdx.y * 16;
    const int col0 = blockIdx.x * 64;   // 0 or 64
    const int w    = t >> 6;        // wave 0..3 -> cols col0 + w*16
    const int l    = t & 63;
    const int g    = l >> 4;        // 0..3
    const int l15  = l & 15;

    f32x4 acc = f32x4{0.f, 0.f, 0.f, 0.f};

    // staging maps
    const int ar = t >> 4;          // A row 0..15 (16 lanes cover 256 B of a row)
    const int aq = t & 15;          // A k sub-lane (float4 -> k = aq*4)
    const int bcol = t >> 2;        // B col-local 0..63
    const int bq   = t & 3;         // B k-quarter -> k = bq*16 (.. +15)

    const float* Arow = &A[(size_t)(row0 + ar) * D_];

    // prologue: issue tile-0 loads into registers
    float4 a_pf = *reinterpret_cast<const float4*>(&Arow[aq * 4]);
    const uint4* bsrc = reinterpret_cast<const uint4*>(
        &Pt[(size_t)0 * 8192 + (col0 + bcol) * 64 + bq * 16]);
    uint4 b_pf0 = bsrc[0];
    uint4 b_pf1 = bsrc[1];

    for (int kk = 0; kk < 16; ++kk) {
        // --- convert & write current tile (consumes prefetch regs)
        {
            const u16 c0 = f2bf(a_pf.x), c1 = f2bf(a_pf.y),
                      c2 = f2bf(a_pf.z), c3 = f2bf(a_pf.w);
            const unsigned lo = (unsigned)c0 | ((unsigned)c1 << 16);
            const unsigned hi = (unsigned)c2 | ((unsigned)c3 << 16);
            *reinterpret_cast<uint2*>(&As[ar][aq * 4]) = make_uint2(lo, hi);
            uint4* bdst = reinterpret_cast<uint4*>(&Bs[bcol][bq * 16]);
            bdst[0] = b_pf0;
            bdst[1] = b_pf1;
        }
        // --- issue next tile's loads (uniform branch; regs now free)
        if (kk + 1 < 16) {
            a_pf = *reinterpret_cast<const float4*>(&Arow[(kk + 1) * 64 + aq * 4]);
            const uint4* bs = reinterpret_cast<const uint4*>(
                &Pt[(size_t)(kk + 1) * 8192 + (col0 + bcol) * 64 + bq * 16]);
            b_pf0 = bs[0];
            b_pf1 = bs[1];
        }
        __syncthreads();

        // --- MFMA: 2 k-steps on this tile
#pragma unroll
        for (int h2 = 0; h2 < 2; ++h2) {
            const short8 a = *reinterpret_cast<const short8*>(
                &As[l15][h2 * 32 + g * 8]);
            const short8 b = *reinterpret_cast<const short8*>(
                &Bs[w * 16 + l15][h2 * 32 + g * 8]);
            acc = __builtin_amdgcn_mfma_f32_16x16x32_bf16(a, b, acc, 0, 0, 0);
        }
        __syncthreads();
    }

    // epilogue: C/D layout col=l15, row=g*4+reg
#pragma unroll
    for (int r = 0; r < 4; ++r) {
        const int row = row0 + g * 4 + r;
        const int col = col0 + w * 16 + l15;
        T[(size_t)row * R_ + col] = f2bf(acc[r]);
    }
}

// ---------------------------------------------------------------------------
// Kernel 3: out[b][i][j] = ni + nj - 2 * (T_i . T_j)   via bf16 MFMA.
// Grid (8,8,8) = 512 blocks; 256 thr = 4 waves; 64x64 tile; K=128 one stage.
// Norms computed in-block from the same bf16 data (diagonal ~ 0).
// Output symmetric in (i,j) => transpose-proof.
// ---------------------------------------------------------------------------
__global__ __launch_bounds__(256) void pairdist_kernel(
    const u16* __restrict__ T,      // [8*512][128] bf16
    float* __restrict__ out)        // [8][512][512] fp32
{
    __shared__ u16 Ti[64][136];     // pad to 136 bf16 = 272 B rows
    __shared__ u16 Tj[64][136];
    __shared__ float ni[64], nj[64];

    const int t  = threadIdx.x;
    const int b  = blockIdx.z;
    const int i0 = blockIdx.y * 64;
    const int j0 = blockIdx.x * 64;
    const u16* Tb = T + (size_t)b * S_ * R_;

    const int w   = t >> 6;
    const int l   = t & 63;
    const int g   = l >> 4;
    const int l15 = l & 15;

    // stage both 64x128 bf16 panels (4x uint4 per thread per panel)
    {
        const int r  = t >> 2;          // 0..63
        const int kq = (t & 3) * 32;    // 0,32,64,96
        const uint4* si = reinterpret_cast<const uint4*>(&Tb[(size_t)(i0 + r) * R_ + kq]);
        const uint4* sj = reinterpret_cast<const uint4*>(&Tb[(size_t)(j0 + r) * R_ + kq]);
        uint4* di = reinterpret_cast<uint4*>(&Ti[r][kq]);
        uint4* dj = reinterpret_cast<uint4*>(&Tj[r][kq]);
#pragma unroll
        for (int p = 0; p < 4; ++p) { di[p] = si[p]; dj[p] = sj[p]; }
    }
    __syncthreads();

    // row norms: threads 0..63 -> Ti rows, 64..127 -> Tj rows
    if (t < 128) {
        const u16* rowp = (t < 64) ? &Ti[t][0] : &Tj[t - 64][0];
        float s = 0.f;
#pragma unroll
        for (int p = 0; p < 16; ++p) {
            const uint4 v = *reinterpret_cast<const uint4*>(rowp + p * 8);
            const unsigned uu[4] = {v.x, v.y, v.z, v.w};
#pragma unroll
            for (int q = 0; q < 4; ++q) {
                const float f0 = bf2f((u16)(uu[q] & 0xffffu));
                const float f1 = bf2f((u16)(uu[q] >> 16));
                s += f0 * f0 + f1 * f1;
            }
        }
        if (t < 64) ni[t] = s; else nj[t - 64] = s;
    }
    __syncthreads();

    // Gram via MFMA: wave w -> rows i0+w*16..+15, n-frags cover 64 j-cols
    f32x4 acc[4];
#pragma unroll
    for (int n = 0; n < 4; ++n) acc[n] = f32x4{0.f, 0.f, 0.f, 0.f};

#pragma unroll
    for (int kk = 0; kk < 4; ++kk) {
        const short8 a = *reinterpret_cast<const short8*>(
            &Ti[w * 16 + l15][kk * 32 + g * 8]);
#pragma unroll
        for (int n = 0; n < 4; ++n) {
            const short8 bb = *reinterpret_cast<const short8*>(
                &Tj[n * 16 + l15][kk * 32 + g * 8]);
            acc[n] = __builtin_amdgcn_mfma_f32_16x16x32_bf16(a, bb, acc[n], 0, 0, 0);
        }
    }

    // epilogue: out = ni[i] + nj[j] - 2*G
    float niv[4];
#pragma unroll
    for (int r = 0; r < 4; ++r) niv[r] = ni[w * 16 + g * 4 + r];
#pragma unroll
    for (int n = 0; n < 4; ++n) {
        const float njv = nj[n * 16 + l15];
#pragma unroll
        for (int r = 0; r < 4; ++r) {
            const int row = i0 + w * 16 + g * 4 + r;
            const int col = j0 + n * 16 + l15;
            out[((size_t)b * S_ + row) * S_ + col] = niv[r] + njv - 2.f * acc[n][r];
        }
    }
}

// ---------------------------------------------------------------------------
extern "C" void kernel_launch(void* const* d_in, const int* in_sizes, int n_in,
                              void* d_out, int out_size, void* d_ws, size_t ws_size,
                              hipStream_t stream) {
    const float* batch = (const float*)d_in[0];   // [8,512,1024] fp32
    const float* proj  = (const float*)d_in[1];   // [1024,128]  fp32
    float* out = (float*)d_out;                   // [8,512,512] fp32

    // ws layout: Pt bf16 [16][128][64] = 256 KB, then T bf16 [4096][128] = 1 MB
    u16* Pt = (u16*)d_ws;
    u16* T  = Pt + 16 * 8192;

    transpose_proj_kernel<<<dim3(16, 4), 256, 0, stream>>>(proj, Pt);
    gemm1_kernel<<<dim3(2, M_ / 16), 256, 0, stream>>>(batch, Pt, T);
    pairdist_kernel<<<dim3(S_ / 64, S_ / 64, B_), 256, 0, stream>>>(T, out);
}